// Round 12
// baseline (438.692 us; speedup 1.0000x reference)
//
#include <hip/hip_runtime.h>
#include <hip/hip_bf16.h>
#include <stdint.h>

#define N_NODES 50000
#define N_PAD   50048   // 782 * 64
#define E_EDGES 800000
#define MT      391     // row tiles of 128 (heads kernel)

typedef __bf16 bf16x8 __attribute__((ext_vector_type(8)));
typedef __bf16 bf16x4 __attribute__((ext_vector_type(4)));
typedef float  f32x4  __attribute__((ext_vector_type(4)));

#define SCAN_B 1024
__global__ void scan_block(const int* __restrict__ cnt, int* __restrict__ ptr,
                           int* __restrict__ bsum, int n) {
    __shared__ int buf[SCAN_B];
    int i = blockIdx.x * SCAN_B + threadIdx.x;
    int v = (i < n) ? cnt[i] : 0;
    buf[threadIdx.x] = v;
    __syncthreads();
    #pragma unroll
    for (int off = 1; off < SCAN_B; off <<= 1) {
        int t = (threadIdx.x >= (unsigned)off) ? buf[threadIdx.x - off] : 0;
        __syncthreads();
        buf[threadIdx.x] += t;
        __syncthreads();
    }
    if (i < n) ptr[i] = buf[threadIdx.x] - v;
    if (threadIdx.x == SCAN_B - 1) bsum[blockIdx.x] = buf[SCAN_B - 1];
}

__global__ void scan_bsums(const int* __restrict__ bsum, int* __restrict__ boff,
                           int nb, int* __restrict__ total_out) {
    __shared__ int buf[SCAN_B];
    int v = ((int)threadIdx.x < nb) ? bsum[threadIdx.x] : 0;
    buf[threadIdx.x] = v;
    __syncthreads();
    #pragma unroll
    for (int off = 1; off < SCAN_B; off <<= 1) {
        int t = (threadIdx.x >= (unsigned)off) ? buf[threadIdx.x - off] : 0;
        __syncthreads();
        buf[threadIdx.x] += t;
        __syncthreads();
    }
    if ((int)threadIdx.x < nb) boff[threadIdx.x] = buf[threadIdx.x] - v;
    if (threadIdx.x == SCAN_B - 1) *total_out = buf[SCAN_B - 1];
}

__global__ void scan_add(int* __restrict__ ptr, const int* __restrict__ boff, int n) {
    int i = blockIdx.x * SCAN_B + threadIdx.x;
    if (i < n) ptr[i] += boff[blockIdx.x];
}

__global__ void fill_csr(const int* __restrict__ ei, const int* __restrict__ ptr,
                         int* __restrict__ cursor, int* __restrict__ col) {
    int e = blockIdx.x * blockDim.x + threadIdx.x;
    if (e < E_EDGES) {
        int dst = ei[E_EDGES + e];
        int pos = ptr[dst] + atomicAdd(&cursor[dst], 1);
        col[pos] = ei[e];
    }
}

// ------- one-shot fp32->bf16 conversion (x + weights) + degree count, fused ----
#define XN      3200000
#define WTOT    983040
__global__ void cvt_count(const float* __restrict__ x,
                          const float* __restrict__ Ws1, const float* __restrict__ Ws2,
                          const float* __restrict__ Ws3, const float* __restrict__ Ws4,
                          const float* __restrict__ Wm1, const float* __restrict__ Wl1,
                          const float* __restrict__ Wm2, const float* __restrict__ Wl2,
                          const int* __restrict__ ei,
                          __bf16* __restrict__ xb, __bf16* __restrict__ wbuf,
                          int* __restrict__ cnt) {
    int i = blockIdx.x * blockDim.x + threadIdx.x;
    if (i < XN) { xb[i] = (__bf16)x[i]; return; }
    int j = i - XN;
    if (j < WTOT) {
        const float* s; int o;
        if      (j <  32768) { s = Ws1; o = j; }
        else if (j < 294912) { s = Ws2; o = j -  32768; }
        else if (j < 557056) { s = Ws3; o = j - 294912; }
        else if (j < 819200) { s = Ws4; o = j - 557056; }
        else if (j < 884736) { s = Wm1; o = j - 819200; }
        else if (j < 950272) { s = Wl1; o = j - 884736; }
        else if (j < 966656) { s = Wm2; o = j - 950272; }
        else                 { s = Wl2; o = j - 966656; }
        wbuf[j] = (__bf16)s[o];
        return;
    }
    int e = j - WTOT;
    if (e < E_EDGES) atomicAdd(&cnt[ei[E_EDGES + e]], 1);
}

// ---------------- aggregation 0: 64-wide rows, 8 lanes x 16B per edge ----------
__global__ __launch_bounds__(256) void agg0_gather(
    const __bf16* __restrict__ xb, const int* __restrict__ ptr,
    const int* __restrict__ col, __bf16* __restrict__ out) {
    int node = blockIdx.x * 4 + (threadIdx.x >> 6);
    int lane = threadIdx.x & 63;
    int g    = lane >> 3;          // edge slot 0..7
    int f0   = (lane & 7) << 3;    // feature chunk base
    if (node >= N_PAD) return;
    long o = (long)node * 64 + f0;
    if (node >= N_NODES) {
        if (g == 0) {
            bf16x8 z;
            #pragma unroll
            for (int i = 0; i < 8; ++i) z[i] = (__bf16)0.0f;
            *(bf16x8*)&out[o] = z;
        }
        return;
    }
    float a[8];
    #pragma unroll
    for (int i = 0; i < 8; ++i) a[i] = 0.0f;
    if (g == 0) {   // self term, added once (slot 0 only)
        bf16x8 s = *(const bf16x8*)&xb[o];
        #pragma unroll
        for (int i = 0; i < 8; ++i) a[i] = (float)s[i];
    }
    int e0 = ptr[node], e1 = ptr[node + 1];
    int e = e0;
    for (; e + 16 <= e1; e += 16) {
        int c0 = col[e + g];
        int c1 = col[e + 8 + g];
        bf16x8 v0 = *(const bf16x8*)&xb[(c0 << 6) + f0];
        bf16x8 v1 = *(const bf16x8*)&xb[(c1 << 6) + f0];
        #pragma unroll
        for (int i = 0; i < 8; ++i) a[i] += (float)v0[i] + (float)v1[i];
    }
    int rem = e1 - e;   // 0..15, wave-uniform
    if (rem > 0) {
        int u0 = (g < rem) ? g : 0;        float m0 = (g < rem) ? 1.0f : 0.0f;
        int i1 = g + 8;
        int u1 = (i1 < rem) ? i1 : 0;      float m1 = (i1 < rem) ? 1.0f : 0.0f;
        int c0 = col[e + u0];
        int c1 = col[e + u1];
        bf16x8 v0 = *(const bf16x8*)&xb[(c0 << 6) + f0];
        bf16x8 v1 = *(const bf16x8*)&xb[(c1 << 6) + f0];
        #pragma unroll
        for (int i = 0; i < 8; ++i) a[i] += m0 * (float)v0[i] + m1 * (float)v1[i];
    }
    #pragma unroll
    for (int i = 0; i < 8; ++i) {
        a[i] += __shfl_xor(a[i], 8, 64);
        a[i] += __shfl_xor(a[i], 16, 64);
        a[i] += __shfl_xor(a[i], 32, 64);
    }
    if (g == 0) {
        bf16x8 r;
        #pragma unroll
        for (int i = 0; i < 8; ++i) r[i] = (__bf16)a[i];
        *(bf16x8*)&out[o] = r;
    }
}

// ---------------- async global->LDS helper -------------------------------------
__device__ __forceinline__ void gl_lds16(const __bf16* g, __bf16* l) {
    __builtin_amdgcn_global_load_lds(
        (const __attribute__((address_space(1))) uint32_t*)g,
        (__attribute__((address_space(3))) uint32_t*)l, 16, 0, 0);
}

// XCD-aware swizzle (proven): NCOL y-tiles of one x-strip share an XCD.
template <int NCOL>
__device__ __forceinline__ void swizzle_xy(int bid, int& x, int& y) {
    int grp  = bid / (8 * NCOL);
    int rem  = bid - grp * (8 * NCOL);
    int base = grp * 8;
    int width = MT - base; if (width > 8) width = 8;
    x = base + rem % width;
    y = rem / width;
}

// ================================================================================
// FUSED shared-MLP + projection — PER-WAVE W SLOTS, barrier-free K-loop
// (r11 winner, 156 µs; LDS-port-bound floor per r11 post-mortem — frozen).
// ================================================================================
#define P_WAITN(n) asm volatile("s_waitcnt vmcnt(" #n ")" ::: "memory")
#define P_WAIT0    asm volatile("s_waitcnt vmcnt(0)" ::: "memory")
#define P_LGKM0    asm volatile("s_waitcnt lgkmcnt(0)" ::: "memory")
#define P_BAR      __builtin_amdgcn_s_barrier()
#define P_SGB      __builtin_amdgcn_sched_barrier(0)
#define SLOTE      2048   // elems per 4 KB per-wave slot

__device__ __forceinline__ void stage_w64(const __bf16* __restrict__ W, int Kdim,
                                          int k0, int wn,
                                          __bf16* __restrict__ slot, int lane) {
    int r16 = lane >> 2, sl = lane & 3;
    #pragma unroll
    for (int i = 0; i < 4; ++i) {
        int rl = i * 16 + r16;
        int kt = sl ^ ((rl >> 1) & 3);
        gl_lds16(W + (long)(wn + rl) * Kdim + k0 + kt * 8, slot + i * 512);
    }
}

__device__ __forceinline__ void stage_wp32(const __bf16* __restrict__ W, int k0,
                                           int wnp, __bf16* __restrict__ slot,
                                           int lane) {
    int r8 = lane >> 3, sl = lane & 7;
    #pragma unroll
    for (int i = 0; i < 4; ++i) {
        int rl = i * 8 + r8;
        int kt = sl ^ (rl & 7);
        gl_lds16(W + (long)(wnp + rl) * 512 + k0 + kt * 8, slot + i * 512);
    }
}

__device__ __forceinline__ void chunk_mfma4L(const __bf16* __restrict__ sAct,
    const __bf16* __restrict__ buf, int c, int rA, int q,
    f32x4 (&acc)[4][4]) {
    const int g   = c * 4 + q;
    const int sla = ((g & 56) | ((g & 7) ^ (rA & 7))) << 3;
    bf16x8 af[4], bfr[4];
    #pragma unroll
    for (int mi = 0; mi < 4; ++mi)
        af[mi] = *(const bf16x8*)&sAct[(mi * 16 + rA) * 512 + sla];
    #pragma unroll
    for (int ni = 0; ni < 4; ++ni) {
        int wrl = ni * 16 + rA;
        bfr[ni] = *(const bf16x8*)&buf[wrl * 32 + ((q ^ ((wrl >> 1) & 3)) << 3)];
    }
    #pragma unroll
    for (int mi = 0; mi < 4; ++mi)
        #pragma unroll
        for (int ni = 0; ni < 4; ++ni)
            acc[mi][ni] = __builtin_amdgcn_mfma_f32_16x16x32_bf16(
                af[mi], bfr[ni], acc[mi][ni], 0, 0, 0);
}

__device__ __forceinline__ void chunk_mfma_a0L(const __bf16* __restrict__ act0,
    const __bf16* __restrict__ buf, int c, int rA, int q,
    f32x4 (&acc)[4][4]) {
    const int g   = c * 4 + q;                  // 0..7
    const int sla = (g ^ (rA & 7)) << 3;
    bf16x8 af[4], bfr[4];
    #pragma unroll
    for (int mi = 0; mi < 4; ++mi)
        af[mi] = *(const bf16x8*)&act0[(mi * 16 + rA) * 64 + sla];
    #pragma unroll
    for (int ni = 0; ni < 4; ++ni) {
        int wrl = ni * 16 + rA;
        bfr[ni] = *(const bf16x8*)&buf[wrl * 32 + ((q ^ ((wrl >> 1) & 3)) << 3)];
    }
    #pragma unroll
    for (int mi = 0; mi < 4; ++mi)
        #pragma unroll
        for (int ni = 0; ni < 4; ++ni)
            acc[mi][ni] = __builtin_amdgcn_mfma_f32_16x16x32_bf16(
                af[mi], bfr[ni], acc[mi][ni], 0, 0, 0);
}

__device__ __forceinline__ void chunk_mfma_projL(const __bf16* __restrict__ sAct,
    const __bf16* __restrict__ buf, int c, int rA, int q,
    f32x4 (&accp)[4][2]) {
    #pragma unroll
    for (int s = 0; s < 2; ++s) {
        const int g   = c * 8 + s * 4 + q;
        const int sla = ((g & 56) | ((g & 7) ^ (rA & 7))) << 3;
        bf16x8 af[4], bfr[2];
        #pragma unroll
        for (int mi = 0; mi < 4; ++mi)
            af[mi] = *(const bf16x8*)&sAct[(mi * 16 + rA) * 512 + sla];
        #pragma unroll
        for (int ni = 0; ni < 2; ++ni) {
            int wrl = ni * 16 + rA;   // 0..31
            int gB  = s * 4 + q;
            bfr[ni] = *(const bf16x8*)&buf[wrl * 64 + ((gB ^ (wrl & 7)) << 3)];
        }
        #pragma unroll
        for (int mi = 0; mi < 4; ++mi)
            #pragma unroll
            for (int ni = 0; ni < 2; ++ni)
                accp[mi][ni] = __builtin_amdgcn_mfma_f32_16x16x32_bf16(
                    af[mi], bfr[ni], accp[mi][ni], 0, 0, 0);
    }
}

template <int ACTn>   // 1 = lrelu(0.1), 2 = relu
__device__ __forceinline__ void writeback_act(__bf16* __restrict__ sAct,
    f32x4 (&acc)[4][4], const float* __restrict__ bv,
    int wn, int ccol, int crow) {
    #pragma unroll
    for (int mi = 0; mi < 4; ++mi)
        #pragma unroll
        for (int ni = 0; ni < 4; ++ni) {
            int cc = wn + ni * 16 + ccol;
            int g  = cc >> 3;
            #pragma unroll
            for (int p = 0; p < 4; ++p) {
                int rr = mi * 16 + crow + p;
                float v = acc[mi][ni][p] + bv[ni];
                if (ACTn == 1) v = (v > 0.0f) ? v : 0.1f * v;
                else           v = fmaxf(v, 0.0f);
                int sl = (g & 56) | ((g & 7) ^ (rr & 7));
                sAct[rr * 512 + sl * 8 + (cc & 7)] = (__bf16)v;
            }
        }
}

template <int ACTn, bool NPROJ>
__device__ __forceinline__ void layer512_wv(
    __bf16* __restrict__ sAct, __bf16* __restrict__ sA, __bf16* __restrict__ sB,
    const __bf16* __restrict__ W, const __bf16* __restrict__ Wn,
    const float* __restrict__ bv,
    int wn, int wnp, int rA, int q, int ccol, int crow, int lane) {
    f32x4 acc[4][4];
    #pragma unroll
    for (int i = 0; i < 4; ++i)
        #pragma unroll
        for (int j = 0; j < 4; ++j) acc[i][j] = (f32x4)0.0f;
    #pragma unroll
    for (int c = 0; c < 16; ++c) {
        P_WAITN(4);                       // own chunk c landed
        __bf16* cur = (c & 1) ? sB : sA;
        chunk_mfma4L(sAct, cur, c, rA, q, acc);
        P_SGB;                            // stage must not hoist above the reads
        if (c <= 13)      stage_w64(W, 512, (c + 2) * 32, wn, cur, lane);
        else if (!NPROJ)  stage_w64(Wn, 512, (c - 14) * 32, wn, cur, lane);
        else              stage_wp32(Wn, (c - 14) * 64, wnp, cur, lane);
    }
    P_BAR;                                // all waves done reading sAct
    writeback_act<ACTn>(sAct, acc, bv, wn, ccol, crow);
    P_LGKM0; P_BAR;                       // writes visible; stages ride across
}

__global__ __launch_bounds__(512) void mlp_fused(
    const __bf16* __restrict__ a0,   // agg0b [N_PAD][64]
    const __bf16* __restrict__ w1, const float* __restrict__ b1,
    const __bf16* __restrict__ w2, const float* __restrict__ b2,
    const __bf16* __restrict__ w3, const float* __restrict__ b3,
    const __bf16* __restrict__ w4, const float* __restrict__ b4,
    const __bf16* __restrict__ wp,   // wml [256][512]
    __bf16* __restrict__ tg)         // t [N_PAD][256]
{
    __shared__ __bf16 lds[69632];    // 136 KB
    __bf16* act0  = lds;             // [64][64]
    __bf16* sAct  = lds + 4096;      // [64][512]
    __bf16* slots = lds + 36864;     // 8 waves x 2 x 2048 elems

    const int tid  = threadIdx.x;
    const int wid  = tid >> 6;
    const int lane = tid & 63;
    const long blockRow = (long)blockIdx.x * 64;

    const int rA   = lane & 15;
    const int q    = lane >> 4;
    const int ccol = lane & 15;
    const int crow = (lane >> 4) << 2;
    const int wn   = wid << 6;       // 512-wide layers
    const int wnp  = wid << 5;       // proj (256-wide)

    __bf16* sA = slots + (wid * 2) * SLOTE;
    __bf16* sB = sA + SLOTE;

    // prologue: act0 (1 gl/wave) + own L1 c0/c1 + bias preload
    {
        int srow = lane >> 3;
        int skg  = (lane & 7) ^ srow;
        gl_lds16(a0 + (blockRow + wid * 8 + srow) * 64 + skg * 8, act0 + wid * 512);
    }
    stage_w64(w1, 64, 0,  wn, sA, lane);   // g0
    stage_w64(w1, 64, 32, wn, sB, lane);   // g1
    float bv1[4], bv2[4], bv3[4], bv4[4];
    #pragma unroll
    for (int ni = 0; ni < 4; ++ni) {
        int idx = wn + ni * 16 + ccol;
        bv1[ni] = b1[idx]; bv2[ni] = b2[idx]; bv3[ni] = b3[idx]; bv4[ni] = b4[idx];
    }

    // one-time full drain (prologue issue order not provably counted) + BAR
    asm volatile("s_waitcnt vmcnt(0) lgkmcnt(0)" ::: "memory");
    P_BAR;

    // ---- L1: 64 -> 512 (A = act0) ----
    {
        f32x4 acc[4][4];
        #pragma unroll
        for (int i = 0; i < 4; ++i)
            #pragma unroll
            for (int j = 0; j < 4; ++j) acc[i][j] = (f32x4)0.0f;
        chunk_mfma_a0L(act0, sA, 0, rA, q, acc);
        P_SGB;
        stage_w64(w2, 512, 0, wn, sA, lane);           // L2 c0
        P_WAITN(4);                                    // no-op (c1 drained); uniform
        chunk_mfma_a0L(act0, sB, 1, rA, q, acc);
        P_SGB;
        stage_w64(w2, 512, 32, wn, sB, lane);          // L2 c1
        P_BAR;                                         // all act0 reads retired
        writeback_act<1>(sAct, acc, bv1, wn, ccol, crow);
        P_LGKM0; P_BAR;
    }

    // ---- L2, L3 (lrelu), L4 (+b4 then relu; next = proj) ----
    layer512_wv<1, false>(sAct, sA, sB, w2, w3, bv2, wn, wnp, rA, q, ccol, crow, lane);
    layer512_wv<1, false>(sAct, sA, sB, w3, w4, bv3, wn, wnp, rA, q, ccol, crow, lane);
    layer512_wv<2, true >(sAct, sA, sB, w4, wp, bv4, wn, wnp, rA, q, ccol, crow, lane);

    // ---- proj: 512 -> 256 (8 chunks of K=64), no bias/act ----
    {
        f32x4 accp[4][2];
        #pragma unroll
        for (int i = 0; i < 4; ++i)
            #pragma unroll
            for (int j = 0; j < 2; ++j) accp[i][j] = (f32x4)0.0f;
        #pragma unroll
        for (int c = 0; c < 8; ++c) {
            if (c == 7) { P_WAIT0; } else { P_WAITN(4); }
            __bf16* cur = (c & 1) ? sB : sA;
            chunk_mfma_projL(sAct, cur, c, rA, q, accp);
            P_SGB;
            if (c <= 5) stage_wp32(wp, (c + 2) * 64, wnp, cur, lane);
        }
        P_BAR;   // all waves' proj reads retired -> slot region reusable
        __bf16* s0 = slots;
        #pragma unroll
        for (int mi = 0; mi < 4; ++mi)
            #pragma unroll
            for (int ni = 0; ni < 2; ++ni)
                #pragma unroll
                for (int p = 0; p < 4; ++p)
                    s0[(mi * 16 + crow + p) * 256 + wnp + ni * 16 + ccol] =
                        (__bf16)accp[mi][ni][p];
        __syncthreads();
        int rr = tid >> 3;
        int c0 = (tid & 7) << 5;
        const bf16x8* s = (const bf16x8*)&s0[rr * 256 + c0];
        __bf16* d = tg + (blockRow + rr) * 256 + c0;
        #pragma unroll
        for (int i = 0; i < 4; ++i) *(bf16x8*)(d + i * 8) = s[i];
    }
}

// ================================================================================
// FUSED second aggregation + head GEMM (r12). One block = 128-row tile x head.
// Phase 1: stage W[128][128] async; gather the block's 128 nodes' neighborhoods
// directly from t (each node: 16 lanes x 16B = the head's 256B half-row; heads
// read DISJOINT cache lines of t, so total gather line traffic == old aggt).
// bias+relu in-register, ds_write into the A tile with the GEMM granule swizzle.
// Phase 2: full drain + barrier, then 128x128 K=128 MFMA GEMM (4 waves, 64x64
// each), fp32 staged epilogue. Eliminates the p buffer round-trip (51 MB).
// 64 KB LDS -> 2 blocks/CU: next block's gather overlaps this block's GEMM.
// LDS layout [128][128] bf16 (A and W): row r, granule g (16 per row) at slot
// (g&8)|((g&7)^(r&7)) -> 2-way bank alias on ds_read_b128 (free).
// ================================================================================
__global__ __launch_bounds__(256) void heads_fused(
    const __bf16* __restrict__ t, const int* __restrict__ ptr,
    const int* __restrict__ col,
    const float* __restrict__ b_m1, const float* __restrict__ b_l1,
    const __bf16* __restrict__ wm2, const float* __restrict__ b_m2,
    float* __restrict__ mu,
    const __bf16* __restrict__ wl2, const float* __restrict__ b_l2,
    float* __restrict__ lv)
{
    __shared__ __bf16 lds[32768];          // A 32KB | W 32KB; epilogue: 64KB f32
    __bf16* Al = lds;                      // [128][128]
    __bf16* Wl = lds + 16384;              // [128][128]

    const int tid  = threadIdx.x;
    const int wid  = tid >> 6;
    const int lane = tid & 63;
    int x, hd;
    swizzle_xy<2>(blockIdx.x, x, hd);
    const long rowBase = (long)x * 128;

    const __bf16* W   = hd ? wl2 : wm2;
    const float*  bs1 = hd ? b_l1 : b_m1;
    const float*  bs2 = hd ? b_l2 : b_m2;
    float*        outp = hd ? lv : mu;
    const int     tcol = hd << 7;

    // stage W async: per wave 8 x 1KB (4 rows each); source granule g chosen so
    // the linear lane-write lands granule g at slot (g&8)|((g&7)^(r&7)).
    {
        int r4  = lane >> 4;
        int gsl = lane & 15;
        #pragma unroll
        for (int i = 0; i < 8; ++i) {
            int row = wid * 32 + i * 4 + r4;
            int g   = (gsl & 8) | ((gsl & 7) ^ (row & 7));
            gl_lds16(W + (long)row * 128 + g * 8, Wl + (wid * 32 + i * 4) * 128);
        }
    }

    // gather + bias + relu -> A tile (8 passes x 16 nodes; 16 lanes per node)
    const int lane16 = tid & 15;           // granule within the 128-col half
    const int ng     = tid >> 4;           // node slot within pass
    f32x4 bg0 = *(const f32x4*)&bs1[lane16 * 8];
    f32x4 bg1 = *(const f32x4*)&bs1[lane16 * 8 + 4];

    for (int pass = 0; pass < 8; ++pass) {
        int  nl   = pass * 16 + ng;        // local row 0..127
        long node = rowBase + nl;
        bf16x8 r;
        if (node < N_NODES) {
            float a[8];
            bf16x8 s = *(const bf16x8*)&t[node * 256 + tcol + lane16 * 8];
            #pragma unroll
            for (int i = 0; i < 8; ++i) a[i] = (float)s[i];
            int e0 = ptr[node], e1 = ptr[node + 1];
            int e = e0;
            for (; e + 8 <= e1; e += 8) {
                int c[8];
                #pragma unroll
                for (int u = 0; u < 8; ++u) c[u] = col[e + u];
                bf16x8 v[8];
                #pragma unroll
                for (int u = 0; u < 8; ++u)
                    v[u] = *(const bf16x8*)&t[(long)c[u] * 256 + tcol + lane16 * 8];
                #pragma unroll
                for (int u = 0; u < 8; ++u)
                    #pragma unroll
                    for (int i = 0; i < 8; ++i) a[i] += (float)v[u][i];
            }
            int rem = e1 - e;   // 0..7
            if (rem > 0) {
                #pragma unroll
                for (int u = 0; u < 7; ++u) {
                    int   uu = (u < rem) ? u : 0;
                    float m  = (u < rem) ? 1.0f : 0.0f;
                    int   cc = col[e + uu];
                    bf16x8 v = *(const bf16x8*)&t[(long)cc * 256 + tcol + lane16 * 8];
                    #pragma unroll
                    for (int i = 0; i < 8; ++i) a[i] += m * (float)v[i];
                }
            }
            #pragma unroll
            for (int i = 0; i < 4; ++i) r[i]     = (__bf16)fmaxf(a[i]     + bg0[i], 0.0f);
            #pragma unroll
            for (int i = 0; i < 4; ++i) r[4 + i] = (__bf16)fmaxf(a[4 + i] + bg1[i], 0.0f);
        } else {
            #pragma unroll
            for (int i = 0; i < 8; ++i) r[i] = (__bf16)0.0f;
        }
        int sl = (lane16 & 8) | ((lane16 & 7) ^ (nl & 7));
        *(bf16x8*)&Al[nl * 128 + sl * 8] = r;
    }

    // output bias (loaded pre-drain so it's covered by the same wait)
    const int rA   = lane & 15;
    const int q    = lane >> 4;
    const int ccol = lane & 15;
    const int crow = (lane >> 4) << 2;
    const int wm   = (wid >> 1) << 6;
    const int wn   = (wid & 1) << 6;
    float bv2[4];
    #pragma unroll
    for (int ni = 0; ni < 4; ++ni) bv2[ni] = bs2[wn + ni * 16 + ccol];

    // drain: W gl_lds + A ds_writes + gathers all retired, then barrier
    asm volatile("s_waitcnt vmcnt(0) lgkmcnt(0)" ::: "memory");
    __syncthreads();

    // GEMM: C[128][128] = A @ W^T, K=128 as 4 chunks of 32
    f32x4 acc[4][4];
    #pragma unroll
    for (int i = 0; i < 4; ++i)
        #pragma unroll
        for (int j = 0; j < 4; ++j) acc[i][j] = (f32x4)0.0f;
    #pragma unroll
    for (int c = 0; c < 4; ++c) {
        const int g = c * 4 + q;
        bf16x8 af[4], bf[4];
        #pragma unroll
        for (int mi = 0; mi < 4; ++mi) {
            int r  = wm + mi * 16 + rA;
            int sl = (g & 8) | ((g & 7) ^ (r & 7));
            af[mi] = *(const bf16x8*)&Al[r * 128 + sl * 8];
        }
        #pragma unroll
        for (int ni = 0; ni < 4; ++ni) {
            int r  = wn + ni * 16 + rA;
            int sl = (g & 8) | ((g & 7) ^ (r & 7));
            bf[ni] = *(const bf16x8*)&Wl[r * 128 + sl * 8];
        }
        #pragma unroll
        for (int mi = 0; mi < 4; ++mi)
            #pragma unroll
            for (int ni = 0; ni < 4; ++ni)
                acc[mi][ni] = __builtin_amdgcn_mfma_f32_16x16x32_bf16(
                    af[mi], bf[ni], acc[mi][ni], 0, 0, 0);
    }

    // epilogue: stage fp32 tile in the (dead) 64 KB LDS, coalesced f32x4 stores
    __syncthreads();                       // all waves' LDS reads retired
    float* fs = (float*)lds;               // [128][128] f32 = 64 KB
    #pragma unroll
    for (int mi = 0; mi < 4; ++mi)
        #pragma unroll
        for (int ni = 0; ni < 4; ++ni)
            #pragma unroll
            for (int p = 0; p < 4; ++p)
                fs[(wm + mi * 16 + crow + p) * 128 + wn + ni * 16 + ccol] =
                    acc[mi][ni][p] + bv2[ni];
    __syncthreads();
    #pragma unroll
    for (int i = 0; i < 16; ++i) {
        int idx = i * 256 + tid;           // f32x4 index in 128x128
        int row = idx >> 5;                // 32 f32x4 per row
        int c0  = (idx & 31) * 4;
        long gr = rowBase + row;
        if (gr < N_NODES)
            *(f32x4*)&outp[gr * 128 + c0] = *(const f32x4*)&fs[idx * 4];
    }
}

extern "C" void kernel_launch(void* const* d_in, const int* in_sizes, int n_in,
                              void* d_out, int out_size, void* d_ws, size_t ws_size,
                              hipStream_t stream) {
    const float* x    = (const float*)d_in[0];
    const int*   ei   = (const int*)d_in[1];
    const float* W_s1 = (const float*)d_in[2];
    const float* b_s1 = (const float*)d_in[3];
    const float* W_s2 = (const float*)d_in[4];
    const float* b_s2 = (const float*)d_in[5];
    const float* W_s3 = (const float*)d_in[6];
    const float* b_s3 = (const float*)d_in[7];
    const float* W_s4 = (const float*)d_in[8];
    const float* b_s4 = (const float*)d_in[9];
    const float* W_m1 = (const float*)d_in[10];
    const float* b_m1 = (const float*)d_in[11];
    const float* W_m2 = (const float*)d_in[12];
    const float* b_m2 = (const float*)d_in[13];
    const float* W_l1 = (const float*)d_in[14];
    const float* b_l1 = (const float*)d_in[15];
    const float* W_l2 = (const float*)d_in[16];
    const float* b_l2 = (const float*)d_in[17];

    char* ws = (char*)d_ws;
    size_t off = 0;
    auto carve = [&](size_t bytes) -> void* {
        void* p = ws + off;
        off = (off + bytes + 255) & ~(size_t)255;
        return p;
    };
    int* ptr  = (int*)carve((size_t)(N_NODES + 1) * 4);
    int* col  = (int*)carve((size_t)E_EDGES * 4);
    int* bsum = (int*)carve(SCAN_B * 4);
    int* boff = (int*)carve(SCAN_B * 4);
    __bf16* wbuf = (__bf16*)carve((size_t)WTOT * 2);
    __bf16* w1  = wbuf;
    __bf16* w2  = wbuf +  32768;
    __bf16* w3  = wbuf + 294912;
    __bf16* w4  = wbuf + 557056;
    __bf16* wml = wbuf + 819200;   // [W_m1 ; W_l1] rows, 256x512
    __bf16* wm2 = wbuf + 950272;
    __bf16* wl2 = wbuf + 966656;
    __bf16* xb    = (__bf16*)carve((size_t)XN * 2);
    __bf16* agg0b = (__bf16*)carve((size_t)N_PAD * 64 * 2);
    __bf16* B1    = (__bf16*)carve((size_t)N_PAD * 512 * 2);
    __bf16* B2    = (__bf16*)carve((size_t)N_PAD * 512 * 2);

    // count/cursor arrays alias B1/B2 — first real writes happen after CSR build
    // completes (stream-ordered).
    int* cnt = (int*)B1;
    int* cur = (int*)B2;

    (void)hipMemsetAsync(cnt, 0, (size_t)N_NODES * 4, stream);
    (void)hipMemsetAsync(cur, 0, (size_t)N_NODES * 4, stream);

    // conversions + degree count (one dispatch)
    cvt_count<<<(XN + WTOT + E_EDGES + 255) / 256, 256, 0, stream>>>(
        x, W_s1, W_s2, W_s3, W_s4, W_m1, W_l1, W_m2, W_l2, ei, xb, wbuf, cnt);

    // CSR build
    const int NB = (N_NODES + SCAN_B - 1) / SCAN_B;  // 49
    scan_block<<<NB, SCAN_B, 0, stream>>>(cnt, ptr, bsum, N_NODES);
    scan_bsums<<<1, SCAN_B, 0, stream>>>(bsum, boff, NB, &ptr[N_NODES]);
    scan_add<<<NB, SCAN_B, 0, stream>>>(ptr, boff, N_NODES);
    fill_csr<<<E_EDGES / 256, 256, 0, stream>>>(ei, ptr, cur, col);

    // first aggregation
    agg0_gather<<<N_PAD / 4, 256, 0, stream>>>(xb, ptr, col, agg0b);

    // fused shared-MLP + projection: agg0b -> t (N_PAD x 256 bf16)
    __bf16* t = B1;
    mlp_fused<<<N_PAD / 64, 512, 0, stream>>>(agg0b, w1, b_s1, w2, b_s2,
                                              w3, b_s3, w4, b_s4, wml, t);

    // fused second aggregation + heads (one swizzled 1D dispatch)
    float* mu = (float*)d_out;
    float* lv = mu + (size_t)N_NODES * 128;
    heads_fused<<<MT * 2, 256, 0, stream>>>(t, ptr, col, b_m1, b_l1,
                                            wm2, b_m2, mu, wl2, b_l2, lv);
}

// Round 13
// 425.404 us; speedup vs baseline: 1.0312x; 1.0312x over previous
//
#include <hip/hip_runtime.h>
#include <hip/hip_bf16.h>
#include <stdint.h>

#define N_NODES 50000
#define N_PAD   50048   // 782 * 64
#define E_EDGES 800000
#define MT      391     // row tiles of 128 (heads kernel)

typedef __bf16 bf16x8 __attribute__((ext_vector_type(8)));
typedef __bf16 bf16x4 __attribute__((ext_vector_type(4)));
typedef float  f32x4  __attribute__((ext_vector_type(4)));

#define SCAN_B 1024
__global__ void scan_block(const int* __restrict__ cnt, int* __restrict__ ptr,
                           int* __restrict__ bsum, int n) {
    __shared__ int buf[SCAN_B];
    int i = blockIdx.x * SCAN_B + threadIdx.x;
    int v = (i < n) ? cnt[i] : 0;
    buf[threadIdx.x] = v;
    __syncthreads();
    #pragma unroll
    for (int off = 1; off < SCAN_B; off <<= 1) {
        int t = (threadIdx.x >= (unsigned)off) ? buf[threadIdx.x - off] : 0;
        __syncthreads();
        buf[threadIdx.x] += t;
        __syncthreads();
    }
    if (i < n) ptr[i] = buf[threadIdx.x] - v;
    if (threadIdx.x == SCAN_B - 1) bsum[blockIdx.x] = buf[SCAN_B - 1];
}

__global__ void scan_bsums(const int* __restrict__ bsum, int* __restrict__ boff,
                           int nb, int* __restrict__ total_out) {
    __shared__ int buf[SCAN_B];
    int v = ((int)threadIdx.x < nb) ? bsum[threadIdx.x] : 0;
    buf[threadIdx.x] = v;
    __syncthreads();
    #pragma unroll
    for (int off = 1; off < SCAN_B; off <<= 1) {
        int t = (threadIdx.x >= (unsigned)off) ? buf[threadIdx.x - off] : 0;
        __syncthreads();
        buf[threadIdx.x] += t;
        __syncthreads();
    }
    if ((int)threadIdx.x < nb) boff[threadIdx.x] = buf[threadIdx.x] - v;
    if (threadIdx.x == SCAN_B - 1) *total_out = buf[SCAN_B - 1];
}

__global__ void scan_add(int* __restrict__ ptr, const int* __restrict__ boff, int n) {
    int i = blockIdx.x * SCAN_B + threadIdx.x;
    if (i < n) ptr[i] += boff[blockIdx.x];
}

__global__ void fill_csr(const int* __restrict__ ei, const int* __restrict__ ptr,
                         int* __restrict__ cursor, int* __restrict__ col) {
    int e = blockIdx.x * blockDim.x + threadIdx.x;
    if (e < E_EDGES) {
        int dst = ei[E_EDGES + e];
        int pos = ptr[dst] + atomicAdd(&cursor[dst], 1);
        col[pos] = ei[e];
    }
}

// ------- one-shot fp32->bf16 conversion (x + weights) + degree count, fused ----
#define XN      3200000
#define WTOT    983040
__global__ void cvt_count(const float* __restrict__ x,
                          const float* __restrict__ Ws1, const float* __restrict__ Ws2,
                          const float* __restrict__ Ws3, const float* __restrict__ Ws4,
                          const float* __restrict__ Wm1, const float* __restrict__ Wl1,
                          const float* __restrict__ Wm2, const float* __restrict__ Wl2,
                          const int* __restrict__ ei,
                          __bf16* __restrict__ xb, __bf16* __restrict__ wbuf,
                          int* __restrict__ cnt) {
    int i = blockIdx.x * blockDim.x + threadIdx.x;
    if (i < XN) { xb[i] = (__bf16)x[i]; return; }
    int j = i - XN;
    if (j < WTOT) {
        const float* s; int o;
        if      (j <  32768) { s = Ws1; o = j; }
        else if (j < 294912) { s = Ws2; o = j -  32768; }
        else if (j < 557056) { s = Ws3; o = j - 294912; }
        else if (j < 819200) { s = Ws4; o = j - 557056; }
        else if (j < 884736) { s = Wm1; o = j - 819200; }
        else if (j < 950272) { s = Wl1; o = j - 884736; }
        else if (j < 966656) { s = Wm2; o = j - 950272; }
        else                 { s = Wl2; o = j - 966656; }
        wbuf[j] = (__bf16)s[o];
        return;
    }
    int e = j - WTOT;
    if (e < E_EDGES) atomicAdd(&cnt[ei[E_EDGES + e]], 1);
}

// ---------------- aggregation 0: 64-wide rows, 8 lanes x 16B per edge ----------
__global__ __launch_bounds__(256) void agg0_gather(
    const __bf16* __restrict__ xb, const int* __restrict__ ptr,
    const int* __restrict__ col, __bf16* __restrict__ out) {
    int node = blockIdx.x * 4 + (threadIdx.x >> 6);
    int lane = threadIdx.x & 63;
    int g    = lane >> 3;          // edge slot 0..7
    int f0   = (lane & 7) << 3;    // feature chunk base
    if (node >= N_PAD) return;
    long o = (long)node * 64 + f0;
    if (node >= N_NODES) {
        if (g == 0) {
            bf16x8 z;
            #pragma unroll
            for (int i = 0; i < 8; ++i) z[i] = (__bf16)0.0f;
            *(bf16x8*)&out[o] = z;
        }
        return;
    }
    float a[8];
    #pragma unroll
    for (int i = 0; i < 8; ++i) a[i] = 0.0f;
    if (g == 0) {   // self term, added once (slot 0 only)
        bf16x8 s = *(const bf16x8*)&xb[o];
        #pragma unroll
        for (int i = 0; i < 8; ++i) a[i] = (float)s[i];
    }
    int e0 = ptr[node], e1 = ptr[node + 1];
    int e = e0;
    for (; e + 16 <= e1; e += 16) {
        int c0 = col[e + g];
        int c1 = col[e + 8 + g];
        bf16x8 v0 = *(const bf16x8*)&xb[(c0 << 6) + f0];
        bf16x8 v1 = *(const bf16x8*)&xb[(c1 << 6) + f0];
        #pragma unroll
        for (int i = 0; i < 8; ++i) a[i] += (float)v0[i] + (float)v1[i];
    }
    int rem = e1 - e;   // 0..15, wave-uniform
    if (rem > 0) {
        int u0 = (g < rem) ? g : 0;        float m0 = (g < rem) ? 1.0f : 0.0f;
        int i1 = g + 8;
        int u1 = (i1 < rem) ? i1 : 0;      float m1 = (i1 < rem) ? 1.0f : 0.0f;
        int c0 = col[e + u0];
        int c1 = col[e + u1];
        bf16x8 v0 = *(const bf16x8*)&xb[(c0 << 6) + f0];
        bf16x8 v1 = *(const bf16x8*)&xb[(c1 << 6) + f0];
        #pragma unroll
        for (int i = 0; i < 8; ++i) a[i] += m0 * (float)v0[i] + m1 * (float)v1[i];
    }
    #pragma unroll
    for (int i = 0; i < 8; ++i) {
        a[i] += __shfl_xor(a[i], 8, 64);
        a[i] += __shfl_xor(a[i], 16, 64);
        a[i] += __shfl_xor(a[i], 32, 64);
    }
    if (g == 0) {
        bf16x8 r;
        #pragma unroll
        for (int i = 0; i < 8; ++i) r[i] = (__bf16)a[i];
        *(bf16x8*)&out[o] = r;
    }
}

// ---------------- aggregation t: r1 winner (44 VGPR, occ ~42%) -----------------
__global__ __launch_bounds__(256) void aggt_gather(
    const __bf16* __restrict__ t, const int* __restrict__ ptr,
    const int* __restrict__ col, const float* __restrict__ b_m1,
    const float* __restrict__ b_l1, __bf16* __restrict__ p) {
    int node = blockIdx.x * 8 + (threadIdx.x >> 5);
    if (node >= N_NODES) return;
    int hl = threadIdx.x & 31;
    int f0 = hl << 3;
    float a[8];
    {
        bf16x8 s = *(const bf16x8*)&t[((long)node << 8) + f0];
        #pragma unroll
        for (int i = 0; i < 8; ++i) a[i] = (float)s[i];
    }
    int e0 = ptr[node], e1 = ptr[node + 1];
    int e = e0;
    for (; e + 8 <= e1; e += 8) {
        int c[8];
        #pragma unroll
        for (int u = 0; u < 8; ++u) c[u] = col[e + u];
        bf16x8 v[8];
        #pragma unroll
        for (int u = 0; u < 8; ++u) v[u] = *(const bf16x8*)&t[((long)c[u] << 8) + f0];
        #pragma unroll
        for (int u = 0; u < 8; ++u)
            #pragma unroll
            for (int i = 0; i < 8; ++i) a[i] += (float)v[u][i];
    }
    int rem = e1 - e;   // 0..7 per node
    if (rem > 0) {
        #pragma unroll
        for (int u = 0; u < 7; ++u) {
            int   uu = (u < rem) ? u : 0;
            float m  = (u < rem) ? 1.0f : 0.0f;
            int   cc = col[e + uu];
            bf16x8 v = *(const bf16x8*)&t[((long)cc << 8) + f0];
            #pragma unroll
            for (int i = 0; i < 8; ++i) a[i] += m * (float)v[i];
        }
    }
    const float* bp = (f0 < 128) ? (b_m1 + f0) : (b_l1 + (f0 - 128));
    f32x4 b0 = *(const f32x4*)bp;
    f32x4 b1 = *(const f32x4*)(bp + 4);
    bf16x8 r;
    #pragma unroll
    for (int i = 0; i < 4; ++i) r[i]     = (__bf16)fmaxf(a[i]     + b0[i], 0.0f);
    #pragma unroll
    for (int i = 0; i < 4; ++i) r[4 + i] = (__bf16)fmaxf(a[4 + i] + b1[i], 0.0f);
    *(bf16x8*)&p[((long)node << 8) + f0] = r;
}

// ---------------- async global->LDS helper -------------------------------------
__device__ __forceinline__ void gl_lds16(const __bf16* g, __bf16* l) {
    __builtin_amdgcn_global_load_lds(
        (const __attribute__((address_space(1))) uint32_t*)g,
        (__attribute__((address_space(3))) uint32_t*)l, 16, 0, 0);
}

// ================================================================================
// FUSED shared-MLP + projection — PER-WAVE W SLOTS, barrier-free K-loop
// (r11 winner, 156 µs; LDS-port-bound floor per r11 post-mortem — frozen).
// Each wave double-buffers its own [64][32] 4KB W slice (4 gl_lds16). vmcnt
// counts per-wave -> NO barrier in the 16-chunk K-loop (sAct is read-only
// within a layer). Waves free-run and drift -> one wave's L2 stage overlaps
// another's LDS/MFMA. Only 2 barriers/layer (writeback). sched_barrier(0)
// after each MFMA cluster pins the same-slot restage.
//
// Per-wave ledger (4 loads/chunk): prologue = act0(1)+c0(4)+c1(4)+biases ->
// full vmcnt(0)+lgkm(0) drain + BAR (one-time). Steady: at chunk c outstanding
// = {c,c+1} = 8 -> vmcnt(4) waits c. Layer boundary: {BAR; writeback; lgkm0;
// BAR} — no vm drain, stages ride across. Proj c==7: only own 4 -> vmcnt(0).
// LDS: act0 8KB | sAct 64KB | 8 waves x 2 x 4KB = 64KB -> 136 KB, 1 block/CU.
// ================================================================================
#define P_WAITN(n) asm volatile("s_waitcnt vmcnt(" #n ")" ::: "memory")
#define P_WAIT0    asm volatile("s_waitcnt vmcnt(0)" ::: "memory")
#define P_LGKM0    asm volatile("s_waitcnt lgkmcnt(0)" ::: "memory")
#define P_BAR      __builtin_amdgcn_s_barrier()
#define P_SGB      __builtin_amdgcn_sched_barrier(0)
#define SLOTE      2048   // elems per 4 KB per-wave slot

// per-wave stage: [64][32] slice, rows wn..wn+63, k0..k0+31 (4 x 1KB)
__device__ __forceinline__ void stage_w64(const __bf16* __restrict__ W, int Kdim,
                                          int k0, int wn,
                                          __bf16* __restrict__ slot, int lane) {
    int r16 = lane >> 2, sl = lane & 3;
    #pragma unroll
    for (int i = 0; i < 4; ++i) {
        int rl = i * 16 + r16;
        int kt = sl ^ ((rl >> 1) & 3);
        gl_lds16(W + (long)(wn + rl) * Kdim + k0 + kt * 8, slot + i * 512);
    }
}

// per-wave proj stage: [32][64] slice, rows wnp..wnp+31 of wp (K=512), k0..k0+63
__device__ __forceinline__ void stage_wp32(const __bf16* __restrict__ W, int k0,
                                           int wnp, __bf16* __restrict__ slot,
                                           int lane) {
    int r8 = lane >> 3, sl = lane & 7;
    #pragma unroll
    for (int i = 0; i < 4; ++i) {
        int rl = i * 8 + r8;
        int kt = sl ^ (rl & 7);
        gl_lds16(W + (long)(wnp + rl) * 512 + k0 + kt * 8, slot + i * 512);
    }
}

__device__ __forceinline__ void chunk_mfma4L(const __bf16* __restrict__ sAct,
    const __bf16* __restrict__ buf, int c, int rA, int q,
    f32x4 (&acc)[4][4]) {
    const int g   = c * 4 + q;
    const int sla = ((g & 56) | ((g & 7) ^ (rA & 7))) << 3;
    bf16x8 af[4], bfr[4];
    #pragma unroll
    for (int mi = 0; mi < 4; ++mi)
        af[mi] = *(const bf16x8*)&sAct[(mi * 16 + rA) * 512 + sla];
    #pragma unroll
    for (int ni = 0; ni < 4; ++ni) {
        int wrl = ni * 16 + rA;   // local row 0..63 (swizzle bits == global's)
        bfr[ni] = *(const bf16x8*)&buf[wrl * 32 + ((q ^ ((wrl >> 1) & 3)) << 3)];
    }
    #pragma unroll
    for (int mi = 0; mi < 4; ++mi)
        #pragma unroll
        for (int ni = 0; ni < 4; ++ni)
            acc[mi][ni] = __builtin_amdgcn_mfma_f32_16x16x32_bf16(
                af[mi], bfr[ni], acc[mi][ni], 0, 0, 0);
}

__device__ __forceinline__ void chunk_mfma_a0L(const __bf16* __restrict__ act0,
    const __bf16* __restrict__ buf, int c, int rA, int q,
    f32x4 (&acc)[4][4]) {
    const int g   = c * 4 + q;                  // 0..7
    const int sla = (g ^ (rA & 7)) << 3;
    bf16x8 af[4], bfr[4];
    #pragma unroll
    for (int mi = 0; mi < 4; ++mi)
        af[mi] = *(const bf16x8*)&act0[(mi * 16 + rA) * 64 + sla];
    #pragma unroll
    for (int ni = 0; ni < 4; ++ni) {
        int wrl = ni * 16 + rA;
        bfr[ni] = *(const bf16x8*)&buf[wrl * 32 + ((q ^ ((wrl >> 1) & 3)) << 3)];
    }
    #pragma unroll
    for (int mi = 0; mi < 4; ++mi)
        #pragma unroll
        for (int ni = 0; ni < 4; ++ni)
            acc[mi][ni] = __builtin_amdgcn_mfma_f32_16x16x32_bf16(
                af[mi], bfr[ni], acc[mi][ni], 0, 0, 0);
}

// proj chunk: per-wave buf [32][64], two sub-k of 8 MFMAs
__device__ __forceinline__ void chunk_mfma_projL(const __bf16* __restrict__ sAct,
    const __bf16* __restrict__ buf, int c, int rA, int q,
    f32x4 (&accp)[4][2]) {
    #pragma unroll
    for (int s = 0; s < 2; ++s) {
        const int g   = c * 8 + s * 4 + q;
        const int sla = ((g & 56) | ((g & 7) ^ (rA & 7))) << 3;
        bf16x8 af[4], bfr[2];
        #pragma unroll
        for (int mi = 0; mi < 4; ++mi)
            af[mi] = *(const bf16x8*)&sAct[(mi * 16 + rA) * 512 + sla];
        #pragma unroll
        for (int ni = 0; ni < 2; ++ni) {
            int wrl = ni * 16 + rA;   // 0..31
            int gB  = s * 4 + q;
            bfr[ni] = *(const bf16x8*)&buf[wrl * 64 + ((gB ^ (wrl & 7)) << 3)];
        }
        #pragma unroll
        for (int mi = 0; mi < 4; ++mi)
            #pragma unroll
            for (int ni = 0; ni < 2; ++ni)
                accp[mi][ni] = __builtin_amdgcn_mfma_f32_16x16x32_bf16(
                    af[mi], bfr[ni], accp[mi][ni], 0, 0, 0);
    }
}

template <int ACTn>   // 1 = lrelu(0.1), 2 = relu
__device__ __forceinline__ void writeback_act(__bf16* __restrict__ sAct,
    f32x4 (&acc)[4][4], const float* __restrict__ bv,
    int wn, int ccol, int crow) {
    #pragma unroll
    for (int mi = 0; mi < 4; ++mi)
        #pragma unroll
        for (int ni = 0; ni < 4; ++ni) {
            int cc = wn + ni * 16 + ccol;
            int g  = cc >> 3;
            #pragma unroll
            for (int p = 0; p < 4; ++p) {
                int rr = mi * 16 + crow + p;
                float v = acc[mi][ni][p] + bv[ni];
                if (ACTn == 1) v = (v > 0.0f) ? v : 0.1f * v;
                else           v = fmaxf(v, 0.0f);
                int sl = (g & 56) | ((g & 7) ^ (rr & 7));
                sAct[rr * 512 + sl * 8 + (cc & 7)] = (__bf16)v;
            }
        }
}

// one 512-wide layer, barrier-free K-loop. c=14/15 stage next layer's c0/c1
// (NPROJ: next is the 512->256 proj with K=64 chunks).
template <int ACTn, bool NPROJ>
__device__ __forceinline__ void layer512_wv(
    __bf16* __restrict__ sAct, __bf16* __restrict__ sA, __bf16* __restrict__ sB,
    const __bf16* __restrict__ W, const __bf16* __restrict__ Wn,
    const float* __restrict__ bv,
    int wn, int wnp, int rA, int q, int ccol, int crow, int lane) {
    f32x4 acc[4][4];
    #pragma unroll
    for (int i = 0; i < 4; ++i)
        #pragma unroll
        for (int j = 0; j < 4; ++j) acc[i][j] = (f32x4)0.0f;
    #pragma unroll
    for (int c = 0; c < 16; ++c) {
        P_WAITN(4);                       // own chunk c landed
        __bf16* cur = (c & 1) ? sB : sA;
        chunk_mfma4L(sAct, cur, c, rA, q, acc);
        P_SGB;                            // stage must not hoist above the reads
        if (c <= 13)      stage_w64(W, 512, (c + 2) * 32, wn, cur, lane);
        else if (!NPROJ)  stage_w64(Wn, 512, (c - 14) * 32, wn, cur, lane);
        else              stage_wp32(Wn, (c - 14) * 64, wnp, cur, lane);
    }
    P_BAR;                                // all waves done reading sAct
    writeback_act<ACTn>(sAct, acc, bv, wn, ccol, crow);
    P_LGKM0; P_BAR;                       // writes visible; stages ride across
}

__global__ __launch_bounds__(512) void mlp_fused(
    const __bf16* __restrict__ a0,   // agg0b [N_PAD][64]
    const __bf16* __restrict__ w1, const float* __restrict__ b1,
    const __bf16* __restrict__ w2, const float* __restrict__ b2,
    const __bf16* __restrict__ w3, const float* __restrict__ b3,
    const __bf16* __restrict__ w4, const float* __restrict__ b4,
    const __bf16* __restrict__ wp,   // wml [256][512]
    __bf16* __restrict__ tg)         // t [N_PAD][256]
{
    __shared__ __bf16 lds[69632];    // 136 KB
    __bf16* act0  = lds;             // [64][64]
    __bf16* sAct  = lds + 4096;      // [64][512]
    __bf16* slots = lds + 36864;     // 8 waves x 2 x 2048 elems

    const int tid  = threadIdx.x;
    const int wid  = tid >> 6;
    const int lane = tid & 63;
    const long blockRow = (long)blockIdx.x * 64;

    const int rA   = lane & 15;
    const int q    = lane >> 4;
    const int ccol = lane & 15;
    const int crow = (lane >> 4) << 2;
    const int wn   = wid << 6;       // 512-wide layers
    const int wnp  = wid << 5;       // proj (256-wide)

    __bf16* sA = slots + (wid * 2) * SLOTE;
    __bf16* sB = sA + SLOTE;

    // prologue: act0 (1 gl/wave) + own L1 c0/c1 + bias preload
    {
        int srow = lane >> 3;
        int skg  = (lane & 7) ^ srow;
        gl_lds16(a0 + (blockRow + wid * 8 + srow) * 64 + skg * 8, act0 + wid * 512);
    }
    stage_w64(w1, 64, 0,  wn, sA, lane);   // g0
    stage_w64(w1, 64, 32, wn, sB, lane);   // g1
    float bv1[4], bv2[4], bv3[4], bv4[4];
    #pragma unroll
    for (int ni = 0; ni < 4; ++ni) {
        int idx = wn + ni * 16 + ccol;
        bv1[ni] = b1[idx]; bv2[ni] = b2[idx]; bv3[ni] = b3[idx]; bv4[ni] = b4[idx];
    }

    // one-time full drain (prologue issue order not provably counted) + BAR
    asm volatile("s_waitcnt vmcnt(0) lgkmcnt(0)" ::: "memory");
    P_BAR;

    // ---- L1: 64 -> 512 (A = act0) ----
    {
        f32x4 acc[4][4];
        #pragma unroll
        for (int i = 0; i < 4; ++i)
            #pragma unroll
            for (int j = 0; j < 4; ++j) acc[i][j] = (f32x4)0.0f;
        chunk_mfma_a0L(act0, sA, 0, rA, q, acc);
        P_SGB;
        stage_w64(w2, 512, 0, wn, sA, lane);           // L2 c0
        P_WAITN(4);                                    // no-op (c1 drained); uniform
        chunk_mfma_a0L(act0, sB, 1, rA, q, acc);
        P_SGB;
        stage_w64(w2, 512, 32, wn, sB, lane);          // L2 c1
        P_BAR;                                         // all act0 reads retired
        writeback_act<1>(sAct, acc, bv1, wn, ccol, crow);
        P_LGKM0; P_BAR;
    }

    // ---- L2, L3 (lrelu), L4 (+b4 then relu; next = proj) ----
    layer512_wv<1, false>(sAct, sA, sB, w2, w3, bv2, wn, wnp, rA, q, ccol, crow, lane);
    layer512_wv<1, false>(sAct, sA, sB, w3, w4, bv3, wn, wnp, rA, q, ccol, crow, lane);
    layer512_wv<2, true >(sAct, sA, sB, w4, wp, bv4, wn, wnp, rA, q, ccol, crow, lane);

    // ---- proj: 512 -> 256 (8 chunks of K=64), no bias/act ----
    {
        f32x4 accp[4][2];
        #pragma unroll
        for (int i = 0; i < 4; ++i)
            #pragma unroll
            for (int j = 0; j < 2; ++j) accp[i][j] = (f32x4)0.0f;
        #pragma unroll
        for (int c = 0; c < 8; ++c) {
            // ledger: c<=6 -> {c,c+1}=8 outstanding, vmcnt(4) waits c;
            // c==7 -> only own 4 in flight, must drain (r5 bug class).
            if (c == 7) { P_WAIT0; } else { P_WAITN(4); }
            __bf16* cur = (c & 1) ? sB : sA;
            chunk_mfma_projL(sAct, cur, c, rA, q, accp);
            P_SGB;
            if (c <= 5) stage_wp32(wp, (c + 2) * 64, wnp, cur, lane);
        }
        P_BAR;   // all waves' proj reads retired -> slot region reusable
        // stage 64x256 bf16 t-tile into the slot region (32 KB), coalesced stores
        __bf16* s0 = slots;
        #pragma unroll
        for (int mi = 0; mi < 4; ++mi)
            #pragma unroll
            for (int ni = 0; ni < 2; ++ni)
                #pragma unroll
                for (int p = 0; p < 4; ++p)
                    s0[(mi * 16 + crow + p) * 256 + wnp + ni * 16 + ccol] =
                        (__bf16)accp[mi][ni][p];
        __syncthreads();
        int rr = tid >> 3;
        int c0 = (tid & 7) << 5;
        const bf16x8* s = (const bf16x8*)&s0[rr * 256 + c0];
        __bf16* d = tg + (blockRow + rr) * 256 + c0;
        #pragma unroll
        for (int i = 0; i < 4; ++i) *(bf16x8*)(d + i * 8) = s[i];
    }
}

// ---------------- 128x128 MFMA GEMM core (heads only now) ----------------------
template <int NCOL>
__device__ __forceinline__ void swizzle_xy(int bid, int& x, int& y) {
    int grp  = bid / (8 * NCOL);
    int rem  = bid - grp * (8 * NCOL);
    int base = grp * 8;
    int width = MT - base; if (width > 8) width = 8;
    x = base + rem % width;
    y = rem / width;
}

template <int ACT, bool BIAS, bool OUT_BF16, bool MCHK>
__device__ __forceinline__ void gemm_core(
    const __bf16* __restrict__ A, int lda, const __bf16* __restrict__ W,
    const float* __restrict__ bias, void* __restrict__ Cout, int ldc,
    int K, long Mstore, long blockRow, int blockCol,
    __bf16* __restrict__ smem) {
    __bf16* As = smem;
    __bf16* Ws = smem + 8192;
    const int tid  = threadIdx.x;
    const int wid  = tid >> 6;
    const int lane = tid & 63;
    const int wm = (wid >> 1) << 6;
    const int wn = (wid & 1) << 6;

    f32x4 acc[4][4];
    #pragma unroll
    for (int i = 0; i < 4; ++i)
        #pragma unroll
        for (int j = 0; j < 4; ++j) acc[i][j] = (f32x4)0.0f;

    const int srow = lane >> 3;
    const int skg  = (lane & 7) ^ srow;
    const __bf16* gA[4]; const __bf16* gW[4];
    __bf16 *lA[4], *lW[4];
    #pragma unroll
    for (int i = 0; i < 4; ++i) {
        int c = wid * 4 + i;
        gA[i] = A + (blockRow + c * 8 + srow) * (long)lda + skg * 8;
        gW[i] = W + ((long)blockCol + c * 8 + srow) * (long)K + skg * 8;
        lA[i] = As + c * 512;
        lW[i] = Ws + c * 512;
    }

    const int rA = lane & 15;
    const int q  = lane >> 4;
    const int r7 = rA & 7;

    for (int k0 = 0; k0 < K; k0 += 64) {
        #pragma unroll
        for (int i = 0; i < 4; ++i) gl_lds16(gA[i] + k0, lA[i]);
        #pragma unroll
        for (int i = 0; i < 4; ++i) gl_lds16(gW[i] + k0, lW[i]);
        __syncthreads();

        #pragma unroll
        for (int s = 0; s < 2; ++s) {
            const int slot = ((s * 4 + q) ^ r7) * 8;
            bf16x8 af[4], bf[4];
            #pragma unroll
            for (int mi = 0; mi < 4; ++mi)
                af[mi] = *(const bf16x8*)&As[(wm + mi * 16 + rA) * 64 + slot];
            #pragma unroll
            for (int ni = 0; ni < 4; ++ni)
                bf[ni] = *(const bf16x8*)&Ws[(wn + ni * 16 + rA) * 64 + slot];
            #pragma unroll
            for (int mi = 0; mi < 4; ++mi)
                #pragma unroll
                for (int ni = 0; ni < 4; ++ni)
                    acc[mi][ni] = __builtin_amdgcn_mfma_f32_16x16x32_bf16(
                        af[mi], bf[ni], acc[mi][ni], 0, 0, 0);
        }
        __syncthreads();
    }

    const int ccol = lane & 15;
    const int crow = (lane >> 4) << 2;
    if (OUT_BF16 && !MCHK) {
        #pragma unroll
        for (int mi = 0; mi < 4; ++mi) {
            #pragma unroll
            for (int ni = 0; ni < 4; ++ni) {
                int gc = wn + ni * 16 + ccol;
                float bv = BIAS ? bias[blockCol + gc] : 0.0f;
                #pragma unroll
                for (int r = 0; r < 4; ++r) {
                    float v = acc[mi][ni][r] + bv;
                    if (ACT == 1) v = (v > 0.0f) ? v : 0.1f * v;
                    else if (ACT == 2) v = fmaxf(v, 0.0f);
                    smem[(wm + mi * 16 + crow + r) * 128 + gc] = (__bf16)v;
                }
            }
        }
        __syncthreads();
        #pragma unroll
        for (int i = 0; i < 8; ++i) {
            int o   = (i * 256 + tid) * 8;
            int row = o >> 7;
            int co  = o & 127;
            *(bf16x8*)((__bf16*)Cout + (blockRow + row) * (long)ldc + blockCol + co) =
                *(const bf16x8*)&smem[o];
        }
    } else if (!OUT_BF16) {
        // fp32 staged path (ldc == 128): two 64-row halves in the dead 32 KB LDS,
        // coalesced f32x4 stores, row-guarded.
        float* fsmem = (float*)smem;
        #pragma unroll
        for (int half = 0; half < 2; ++half) {
            __syncthreads();
            if ((wm >> 6) == half) {
                #pragma unroll
                for (int mi = 0; mi < 4; ++mi) {
                    #pragma unroll
                    for (int ni = 0; ni < 4; ++ni) {
                        int gc = wn + ni * 16 + ccol;
                        float bv = BIAS ? bias[blockCol + gc] : 0.0f;
                        #pragma unroll
                        for (int r = 0; r < 4; ++r) {
                            float v = acc[mi][ni][r] + bv;
                            if (ACT == 1) v = (v > 0.0f) ? v : 0.1f * v;
                            else if (ACT == 2) v = fmaxf(v, 0.0f);
                            fsmem[(mi * 16 + crow + r) * 128 + gc] = v;
                        }
                    }
                }
            }
            __syncthreads();
            #pragma unroll
            for (int i = 0; i < 8; ++i) {
                int o   = i * 256 + tid;
                int row = o >> 5;
                int co  = (o & 31) * 4;
                long gr = blockRow + half * 64 + row;
                if (!MCHK || gr < Mstore)
                    *(f32x4*)((float*)Cout + gr * (long)ldc + blockCol + co) =
                        *(const f32x4*)&fsmem[o * 4];
            }
        }
    } else {
        #pragma unroll
        for (int mi = 0; mi < 4; ++mi) {
            #pragma unroll
            for (int ni = 0; ni < 4; ++ni) {
                long gr0 = blockRow + wm + mi * 16 + crow;
                int  gc  = blockCol + wn + ni * 16 + ccol;
                float bv = BIAS ? bias[gc] : 0.0f;
                #pragma unroll
                for (int r = 0; r < 4; ++r) {
                    long gr = gr0 + r;
                    if (!MCHK || gr < Mstore) {
                        float v = acc[mi][ni][r] + bv;
                        if (ACT == 1) v = (v > 0.0f) ? v : 0.1f * v;
                        else if (ACT == 2) v = fmaxf(v, 0.0f);
                        ((__bf16*)Cout)[gr * ldc + gc] = (__bf16)v;
                    }
                }
            }
        }
    }
}

// both heads in one 1D dispatch; K=128 (each head uses its half of p), lda=256.
__global__ __launch_bounds__(256) void gemm_heads(
    const __bf16* __restrict__ p, const __bf16* __restrict__ wm2,
    const float* __restrict__ b_m2, float* __restrict__ mu,
    const __bf16* __restrict__ wl2, const float* __restrict__ b_l2,
    float* __restrict__ lv) {
    __shared__ __bf16 smem[128 * 128];
    int x, hd;
    swizzle_xy<2>(blockIdx.x, x, hd);
    if (hd == 0)
        gemm_core<0, true, false, true>(p, 256, wm2, b_m2, mu, 128, 128, N_NODES,
                                        (long)x * 128, 0, smem);
    else
        gemm_core<0, true, false, true>(p + 128, 256, wl2, b_l2, lv, 128, 128, N_NODES,
                                        (long)x * 128, 0, smem);
}

extern "C" void kernel_launch(void* const* d_in, const int* in_sizes, int n_in,
                              void* d_out, int out_size, void* d_ws, size_t ws_size,
                              hipStream_t stream) {
    const float* x    = (const float*)d_in[0];
    const int*   ei   = (const int*)d_in[1];
    const float* W_s1 = (const float*)d_in[2];
    const float* b_s1 = (const float*)d_in[3];
    const float* W_s2 = (const float*)d_in[4];
    const float* b_s2 = (const float*)d_in[5];
    const float* W_s3 = (const float*)d_in[6];
    const float* b_s3 = (const float*)d_in[7];
    const float* W_s4 = (const float*)d_in[8];
    const float* b_s4 = (const float*)d_in[9];
    const float* W_m1 = (const float*)d_in[10];
    const float* b_m1 = (const float*)d_in[11];
    const float* W_m2 = (const float*)d_in[12];
    const float* b_m2 = (const float*)d_in[13];
    const float* W_l1 = (const float*)d_in[14];
    const float* b_l1 = (const float*)d_in[15];
    const float* W_l2 = (const float*)d_in[16];
    const float* b_l2 = (const float*)d_in[17];

    char* ws = (char*)d_ws;
    size_t off = 0;
    auto carve = [&](size_t bytes) -> void* {
        void* p = ws + off;
        off = (off + bytes + 255) & ~(size_t)255;
        return p;
    };
    int* ptr  = (int*)carve((size_t)(N_NODES + 1) * 4);
    int* col  = (int*)carve((size_t)E_EDGES * 4);
    int* bsum = (int*)carve(SCAN_B * 4);
    int* boff = (int*)carve(SCAN_B * 4);
    __bf16* wbuf = (__bf16*)carve((size_t)WTOT * 2);
    __bf16* w1  = wbuf;
    __bf16* w2  = wbuf +  32768;
    __bf16* w3  = wbuf + 294912;
    __bf16* w4  = wbuf + 557056;
    __bf16* wml = wbuf + 819200;   // [W_m1 ; W_l1] rows, 256x512
    __bf16* wm2 = wbuf + 950272;
    __bf16* wl2 = wbuf + 966656;
    __bf16* xb    = (__bf16*)carve((size_t)XN * 2);
    __bf16* agg0b = (__bf16*)carve((size_t)N_PAD * 64 * 2);
    __bf16* B1    = (__bf16*)carve((size_t)N_PAD * 512 * 2);
    __bf16* B2    = (__bf16*)carve((size_t)N_PAD * 512 * 2);

    // count/cursor arrays alias B1/B2 — first real writes happen after CSR build
    // completes (stream-ordered).
    int* cnt = (int*)B1;
    int* cur = (int*)B2;

    (void)hipMemsetAsync(cnt, 0, (size_t)N_NODES * 4, stream);
    (void)hipMemsetAsync(cur, 0, (size_t)N_NODES * 4, stream);

    // conversions + degree count (one dispatch)
    cvt_count<<<(XN + WTOT + E_EDGES + 255) / 256, 256, 0, stream>>>(
        x, W_s1, W_s2, W_s3, W_s4, W_m1, W_l1, W_m2, W_l2, ei, xb, wbuf, cnt);

    // CSR build
    const int NB = (N_NODES + SCAN_B - 1) / SCAN_B;  // 49
    scan_block<<<NB, SCAN_B, 0, stream>>>(cnt, ptr, bsum, N_NODES);
    scan_bsums<<<1, SCAN_B, 0, stream>>>(bsum, boff, NB, &ptr[N_NODES]);
    scan_add<<<NB, SCAN_B, 0, stream>>>(ptr, boff, N_NODES);
    fill_csr<<<E_EDGES / 256, 256, 0, stream>>>(ei, ptr, cur, col);

    // first aggregation
    agg0_gather<<<N_PAD / 4, 256, 0, stream>>>(xb, ptr, col, agg0b);

    // fused shared-MLP + projection: agg0b -> t (N_PAD x 256 bf16)
    __bf16* t = B1;
    mlp_fused<<<N_PAD / 64, 512, 0, stream>>>(agg0b, w1, b_s1, w2, b_s2,
                                              w3, b_s3, w4, b_s4, wml, t);

    // second aggregation, fused bias+relu
    __bf16* p = B2;  // N x 256 bf16
    aggt_gather<<<(N_NODES + 7) / 8, 256, 0, stream>>>(t, ptr, col, b_m1, b_l1, p);

    // heads (one swizzled 1D dispatch)
    float* mu = (float*)d_out;
    float* lv = mu + (size_t)N_NODES * 128;
    gemm_heads<<<MT * 2, 256, 0, stream>>>(p, wm2, b_m2, mu, wl2, b_l2, lv);
}